// Round 3
// baseline (584.004 us; speedup 1.0000x reference)
//
#include <hip/hip_runtime.h>
#include <hip/hip_bf16.h>
#include <math.h>

#define MTOK 16384   // B*N = 4*4096

typedef __attribute__((ext_vector_type(8))) short bf16x8;
typedef __attribute__((ext_vector_type(4))) float f32x4;

__device__ __forceinline__ float bf2f(ushort u) {
  union { unsigned int u; float f; } c; c.u = ((unsigned int)u) << 16; return c.f;
}
__device__ __forceinline__ ushort f2bf(float f) {
  union { float f; unsigned int u; } c; c.f = f;
  unsigned int r = c.u + 0x7fffu + ((c.u >> 16) & 1u);
  return (ushort)(r >> 16);
}

__device__ __forceinline__ void gload_lds16(const void* g, void* l) {
  __builtin_amdgcn_global_load_lds(
      (const __attribute__((address_space(1))) unsigned int*)g,
      (__attribute__((address_space(3))) unsigned int*)l, 16, 0, 0);
}

// ---------------- fp32 -> bf16 convert (weights) ----------------
__global__ __launch_bounds__(256)
void f32_to_bf16_k(const float* __restrict__ in, ushort* __restrict__ out, int n4) {
  int i = blockIdx.x * 256 + threadIdx.x;
  if (i >= n4) return;
  float4 v = *(const float4*)&in[(size_t)i * 4];
  ushort4 o;
  o.x = f2bf(v.x); o.y = f2bf(v.y); o.z = f2bf(v.z); o.w = f2bf(v.w);
  *(ushort4*)&out[(size_t)i * 4] = o;
}

// ---------------- RMSNorm: fp32 in -> bf16 out ----------------
__global__ __launch_bounds__(256)
void rmsnorm_k(const float* __restrict__ x, const float* __restrict__ scale,
               ushort* __restrict__ out) {
  __shared__ float red[4];
  int row = blockIdx.x;
  int t = threadIdx.x;
  const float* xr = x + (size_t)row * 1024;
  float4 v = *(const float4*)&xr[t * 4];
  float s = v.x*v.x + v.y*v.y + v.z*v.z + v.w*v.w;
  #pragma unroll
  for (int off = 32; off > 0; off >>= 1) s += __shfl_xor(s, off);
  if ((t & 63) == 0) red[t >> 6] = s;
  __syncthreads();
  float tot = red[0] + red[1] + red[2] + red[3];
  float rn = (32.0f + 1e-6f) / sqrtf(tot);
  float4 sc = *(const float4*)&scale[t * 4];
  ushort4 o;
  o.x = f2bf(v.x * rn * sc.x);
  o.y = f2bf(v.y * rn * sc.y);
  o.z = f2bf(v.z * rn * sc.z);
  o.w = f2bf(v.w * rn * sc.w);
  *(ushort4*)&out[(size_t)row * 1024 + t * 4] = o;
}

// ======== 256x256 deep-pipelined bf16 MFMA GEMM: out[M,F] = A[M,K] @ W[F,K]^T ========
// 8 waves (2M x 4N), BK=64, 128KiB LDS double-buffer, fragment-ordered LDS layout
// (each MFMA operand read = contiguous 1KB -> conflict-free; gload_lds lane-linear).
// Pipeline: iter T computes buf b=T&1; stages B(T+1)->b^1 in ph0/ph1; after A-drain
// barrier stages A(T+2)->b in ph3. Boundary wait: vmcnt(4) (vmcnt(0) at the tail).
// EPI 0: qkv — q(phi) token-major; k(phi)/v transposed [b,h,ch,n]
// EPI 1: outf32 = resid + gamma*(acc+bias)
// EPI 2: gelu(acc+bias) bf16
template<int EPI>
__global__ __launch_bounds__(512, 2)
void gemm256(const ushort* __restrict__ A, const ushort* __restrict__ W,
             void* __restrict__ outp, const float* __restrict__ bias,
             const float* __restrict__ gamma, const float* __restrict__ resid,
             ushort* __restrict__ kTp, ushort* __restrict__ vTp,
             int nBn, int K) {
  __shared__ ushort lds[65536];   // 128 KiB: [buf][A 32K | B 32K]
  const int tid = threadIdx.x;
  const int lane = tid & 63;
  const int w = tid >> 6;             // 0..7
  const int wm = w >> 2, wn = w & 3;  // 2 x 4 wave grid
  const int frow = lane & 15, kq = lane >> 4;
  const int F = nBn << 8;

  // bijective XCD swizzle (grid % 8 == 0 for all our launches)
  const int swz = ((int)blockIdx.x & 7) * ((int)gridDim.x >> 3) + ((int)blockIdx.x >> 3);
  const int bm = swz / nBn, bn = swz % nBn;
  const int brow = bm << 8, bcol = bn << 8;

  // staging source bases: wave w stages frag-row w of each 128-row half
  const int srow = (w << 4) + frow;
  const ushort* pa = A + (size_t)(brow + srow) * K + (kq << 3);
  const ushort* pb = W + (size_t)(bcol + srow) * K + (kq << 3);
  const int sdA = w << 10;              // lds ushort idx (+ b*32768 + h*8192)
  const int sdB = 16384 + (w << 10);
  // read bases (ushort idx): + b*32768 + frag*1024 + ks*512
  const int ra = (wm << 13) + (lane << 3);
  const int rb = 16384 + ((wn >> 1) << 13) + ((wn & 1) << 12) + (lane << 3);

  auto stA = [&](int b, int h, int k0) {
    const ushort* s = pa + (size_t)(h << 7) * K + k0;
    ushort* d = &lds[(b << 15) + (h << 13) + sdA];
    gload_lds16(s, d);
    gload_lds16(s + 32, d + 512);
  };
  auto stB = [&](int b, int h, int k0) {
    const ushort* s = pb + (size_t)(h << 7) * K + k0;
    ushort* d = &lds[(b << 15) + (h << 13) + sdB];
    gload_lds16(s, d);
    gload_lds16(s + 32, d + 512);
  };

  const int NT = K >> 6;
  // prologue: A(T0),B(T0)->buf0 ; A(T1)->buf1
  stA(0, 0, 0); stA(0, 1, 0);
  stB(0, 0, 0); stB(0, 1, 0);
  stA(1, 0, 64); stA(1, 1, 64);
  asm volatile("s_waitcnt vmcnt(4)\ns_barrier" ::: "memory");

  f32x4 acc[8][4];
  #pragma unroll
  for (int i = 0; i < 8; ++i)
    #pragma unroll
    for (int j = 0; j < 4; ++j) acc[i][j] = (f32x4){0.f, 0.f, 0.f, 0.f};

  for (int t = 0; t < NT; ++t) {
    const int b = t & 1, bb = b << 15;
    bf16x8 ar[4][2], br[2][2];

    // ---- phase 0: stage B(T+1) h0; read A-lo + B-q0; mfma C(0,0) ----
    if (t + 1 < NT) stB(b ^ 1, 0, (t + 1) << 6);
    #pragma unroll
    for (int mi = 0; mi < 4; ++mi)
      #pragma unroll
      for (int ks = 0; ks < 2; ++ks)
        ar[mi][ks] = *(const bf16x8*)&lds[bb + ra + (mi << 10) + (ks << 9)];
    #pragma unroll
    for (int ni = 0; ni < 2; ++ni)
      #pragma unroll
      for (int ks = 0; ks < 2; ++ks)
        br[ni][ks] = *(const bf16x8*)&lds[bb + rb + (ni << 10) + (ks << 9)];
    __builtin_amdgcn_s_setprio(1);
    #pragma unroll
    for (int mi = 0; mi < 4; ++mi)
      #pragma unroll
      for (int ni = 0; ni < 2; ++ni)
        #pragma unroll
        for (int ks = 0; ks < 2; ++ks)
          acc[mi][ni] = __builtin_amdgcn_mfma_f32_16x16x32_bf16(
              ar[mi][ks], br[ni][ks], acc[mi][ni], 0, 0, 0);
    __builtin_amdgcn_s_setprio(0);

    // ---- phase 1: stage B(T+1) h1; read B-q1; mfma C(0,1) ----
    if (t + 1 < NT) stB(b ^ 1, 1, (t + 1) << 6);
    #pragma unroll
    for (int ni = 0; ni < 2; ++ni)
      #pragma unroll
      for (int ks = 0; ks < 2; ++ks)
        br[ni][ks] = *(const bf16x8*)&lds[bb + rb + ((2 + ni) << 10) + (ks << 9)];
    __builtin_amdgcn_s_setprio(1);
    #pragma unroll
    for (int mi = 0; mi < 4; ++mi)
      #pragma unroll
      for (int ni = 0; ni < 2; ++ni)
        #pragma unroll
        for (int ks = 0; ks < 2; ++ks)
          acc[mi][2 + ni] = __builtin_amdgcn_mfma_f32_16x16x32_bf16(
              ar[mi][ks], br[ni][ks], acc[mi][2 + ni], 0, 0, 0);
    __builtin_amdgcn_s_setprio(0);

    // ---- phase 2: read A-hi; mfma C(1,1) ----
    #pragma unroll
    for (int mi = 0; mi < 4; ++mi)
      #pragma unroll
      for (int ks = 0; ks < 2; ++ks)
        ar[mi][ks] = *(const bf16x8*)&lds[bb + ra + ((4 + mi) << 10) + (ks << 9)];
    __builtin_amdgcn_s_setprio(1);
    #pragma unroll
    for (int mi = 0; mi < 4; ++mi)
      #pragma unroll
      for (int ni = 0; ni < 2; ++ni)
        #pragma unroll
        for (int ks = 0; ks < 2; ++ks)
          acc[4 + mi][2 + ni] = __builtin_amdgcn_mfma_f32_16x16x32_bf16(
              ar[mi][ks], br[ni][ks], acc[4 + mi][2 + ni], 0, 0, 0);
    __builtin_amdgcn_s_setprio(0);

    // ---- barrier A: all waves' A-reads of buf b drained -> A region reusable ----
    asm volatile("s_waitcnt lgkmcnt(0)\ns_barrier" ::: "memory");

    // ---- phase 3: stage A(T+2)->buf b; re-read B-q0; mfma C(1,0) ----
    if (t + 2 < NT) { stA(b, 0, (t + 2) << 6); stA(b, 1, (t + 2) << 6); }
    #pragma unroll
    for (int ni = 0; ni < 2; ++ni)
      #pragma unroll
      for (int ks = 0; ks < 2; ++ks)
        br[ni][ks] = *(const bf16x8*)&lds[bb + rb + (ni << 10) + (ks << 9)];
    __builtin_amdgcn_s_setprio(1);
    #pragma unroll
    for (int mi = 0; mi < 4; ++mi)
      #pragma unroll
      for (int ni = 0; ni < 2; ++ni)
        #pragma unroll
        for (int ks = 0; ks < 2; ++ks)
          acc[4 + mi][ni] = __builtin_amdgcn_mfma_f32_16x16x32_bf16(
              ar[mi][ks], br[ni][ks], acc[4 + mi][ni], 0, 0, 0);
    __builtin_amdgcn_s_setprio(0);

    // ---- barrier B: counted vmcnt — next tile's A+B guaranteed landed ----
    if (t + 2 < NT)
      asm volatile("s_waitcnt lgkmcnt(0) vmcnt(4)\ns_barrier" ::: "memory");
    else
      asm volatile("s_waitcnt lgkmcnt(0) vmcnt(0)\ns_barrier" ::: "memory");
  }

  // ---- epilogue: C row = brow+wm*128+mi*16+kq*4+r, col = bcol+wn*64+ni*16+frow ----
  #pragma unroll
  for (int mi = 0; mi < 8; ++mi) {
    #pragma unroll
    for (int ni = 0; ni < 4; ++ni) {
      int col = bcol + (wn << 6) + (ni << 4) + frow;
      int rbase = brow + (wm << 7) + (mi << 4) + (kq << 2);
      if (EPI == 0) {
        if (col < 1024) {
          #pragma unroll
          for (int r = 0; r < 4; ++r) {
            float v = acc[mi][ni][r];
            ((ushort*)outp)[(size_t)(rbase + r) * 1024 + col] =
                f2bf(__expf(-0.5f * v * v));
          }
        } else {
          bool isk = col < 2048;
          int c = col - (isk ? 1024 : 2048);
          int b = rbase >> 12, n = rbase & 4095;
          ushort4 o;
          #pragma unroll
          for (int r = 0; r < 4; ++r) {
            float v = acc[mi][ni][r];
            if (isk) v = __expf(-0.5f * v * v);
            ((ushort*)&o)[r] = f2bf(v);
          }
          ushort* dst = (isk ? kTp : vTp) +
                        ((size_t)(b * 16 + (c >> 6)) * 64 + (c & 63)) * 4096 + n;
          *(ushort4*)dst = o;
        }
      } else {
        #pragma unroll
        for (int r = 0; r < 4; ++r) {
          int row = rbase + r;
          float v = acc[mi][ni][r];
          size_t idx = (size_t)row * F + col;
          if (EPI == 1) {
            ((float*)outp)[idx] = resid[idx] + gamma[col] * (v + bias[col]);
          } else {
            float t2 = v + bias[col];
            ((ushort*)outp)[idx] =
                f2bf(0.5f * t2 * (1.0f + erff(t2 * 0.70710678118f)));
          }
        }
      }
    }
  }
}

// ---------------- kvT[b,h,e,d] = sum_n v[n,e]*k[n,d]  (MFMA, split-K) ----------------
__global__ __launch_bounds__(256)
void attn_kv_mfma(const ushort* __restrict__ kT, const ushort* __restrict__ vT,
                  float* __restrict__ kvT, float* __restrict__ ksum) {
  __shared__ float red[4][4096];
  int bi = blockIdx.x;
  int ksl = bi & 7, h = (bi >> 3) & 15, b = bi >> 7;
  int tid = threadIdx.x, lane = tid & 63, w = tid >> 6;
  int frow = lane & 15, kq = lane >> 4;
  const size_t bh = (size_t)(b * 16 + h) * 64;
  const ushort* vb = vT + bh * 4096;
  const ushort* kb = kT + bh * 4096;
  int tk0 = ksl * 512 + w * 128;

  f32x4 acc[4][4];
  #pragma unroll
  for (int i = 0; i < 4; ++i)
    #pragma unroll
    for (int j = 0; j < 4; ++j) acc[i][j] = (f32x4){0.f, 0.f, 0.f, 0.f};
  float kpart[4] = {0.f, 0.f, 0.f, 0.f};

  #pragma unroll
  for (int kstep = 0; kstep < 4; ++kstep) {
    int tok = tk0 + kstep * 32 + kq * 8;
    bf16x8 af[4], bfr[4];
    #pragma unroll
    for (int mi = 0; mi < 4; ++mi)
      af[mi] = *(const bf16x8*)&vb[(size_t)(mi * 16 + frow) * 4096 + tok];
    #pragma unroll
    for (int ni = 0; ni < 4; ++ni) {
      bfr[ni] = *(const bf16x8*)&kb[(size_t)(ni * 16 + frow) * 4096 + tok];
      #pragma unroll
      for (int j = 0; j < 8; ++j) kpart[ni] += bf2f((ushort)bfr[ni][j]);
    }
    #pragma unroll
    for (int mi = 0; mi < 4; ++mi)
      #pragma unroll
      for (int ni = 0; ni < 4; ++ni)
        acc[mi][ni] = __builtin_amdgcn_mfma_f32_16x16x32_bf16(
            af[mi], bfr[ni], acc[mi][ni], 0, 0, 0);
  }

  #pragma unroll
  for (int ni = 0; ni < 4; ++ni) {
    kpart[ni] += __shfl_xor(kpart[ni], 16);
    kpart[ni] += __shfl_xor(kpart[ni], 32);
  }
  if (lane < 16) {
    #pragma unroll
    for (int ni = 0; ni < 4; ++ni)
      atomicAdd(&ksum[(b * 16 + h) * 64 + ni * 16 + frow], kpart[ni]);
  }

  #pragma unroll
  for (int mi = 0; mi < 4; ++mi)
    #pragma unroll
    for (int ni = 0; ni < 4; ++ni)
      #pragma unroll
      for (int r = 0; r < 4; ++r)
        red[w][(mi * 16 + kq * 4 + r) * 64 + ni * 16 + frow] = acc[mi][ni][r];
  __syncthreads();
  float* kvg = kvT + (size_t)(b * 16 + h) * 4096;
  for (int i = tid; i < 4096; i += 256) {
    float s = red[0][i] + red[1][i] + red[2][i] + red[3][i];
    atomicAdd(&kvg[i], s);
  }
}

// ---------------- out[n,e] = z * sum_d q[n,d]*kvT[e,d]  (MFMA) ----------------
__global__ __launch_bounds__(256)
void attn_out_mfma(const ushort* __restrict__ qb, const float* __restrict__ kvT,
                   const float* __restrict__ ksum, ushort* __restrict__ ao) {
  __shared__ ushort skv[64 * 72];
  __shared__ float sks[64];
  int bi = blockIdx.x;
  int c = bi & 15, h = (bi >> 4) & 15, b = bi >> 8;
  int tid = threadIdx.x, lane = tid & 63, w = tid >> 6;
  int frow = lane & 15, kq = lane >> 4;
  const float* kvg = kvT + (size_t)(b * 16 + h) * 4096;
  for (int i = tid; i < 4096; i += 256)
    skv[(i >> 6) * 72 + (i & 63)] = f2bf(kvg[i]);
  if (tid < 64) sks[tid] = ksum[(b * 16 + h) * 64 + tid];
  __syncthreads();

  int m0 = b * 4096 + c * 256 + w * 64;
  f32x4 acc[4][4];
  #pragma unroll
  for (int i = 0; i < 4; ++i)
    #pragma unroll
    for (int j = 0; j < 4; ++j) acc[i][j] = (f32x4){0.f, 0.f, 0.f, 0.f};
  float dp[4] = {0.f, 0.f, 0.f, 0.f};

  #pragma unroll
  for (int kst = 0; kst < 2; ++kst) {
    int d0 = kst * 32 + kq * 8;
    bf16x8 af[4], bfr[4];
    #pragma unroll
    for (int mi = 0; mi < 4; ++mi)
      af[mi] = *(const bf16x8*)&qb[(size_t)(m0 + mi * 16 + frow) * 1024 + h * 64 + d0];
    #pragma unroll
    for (int ni = 0; ni < 4; ++ni)
      bfr[ni] = *(const bf16x8*)&skv[(ni * 16 + frow) * 72 + d0];
    #pragma unroll
    for (int mi = 0; mi < 4; ++mi) {
      float s = 0.f;
      #pragma unroll
      for (int j = 0; j < 8; ++j) s += bf2f((ushort)af[mi][j]) * sks[d0 + j];
      dp[mi] += s;
    }
    #pragma unroll
    for (int mi = 0; mi < 4; ++mi)
      #pragma unroll
      for (int ni = 0; ni < 4; ++ni)
        acc[mi][ni] = __builtin_amdgcn_mfma_f32_16x16x32_bf16(
            af[mi], bfr[ni], acc[mi][ni], 0, 0, 0);
  }

  #pragma unroll
  for (int mi = 0; mi < 4; ++mi) {
    dp[mi] += __shfl_xor(dp[mi], 16);
    dp[mi] += __shfl_xor(dp[mi], 32);
  }

  #pragma unroll
  for (int mi = 0; mi < 4; ++mi)
    #pragma unroll
    for (int ni = 0; ni < 4; ++ni)
      #pragma unroll
      for (int r = 0; r < 4; ++r) {
        float dotv = __shfl(dp[mi], (kq << 2) + r);
        float z = 1.f / (dotv + 1e-6f);
        int mrow = m0 + mi * 16 + kq * 4 + r;
        ao[(size_t)mrow * 1024 + h * 64 + ni * 16 + frow] =
            f2bf(acc[mi][ni][r] * z);
      }
}

extern "C" void kernel_launch(void* const* d_in, const int* in_sizes, int n_in,
                              void* d_out, int out_size, void* d_ws, size_t ws_size,
                              hipStream_t stream) {
  const float* x       = (const float*)d_in[0];
  const float* scale1  = (const float*)d_in[1];
  const float* scale2  = (const float*)d_in[2];
  const float* gamma   = (const float*)d_in[3];
  const float* qkv_w   = (const float*)d_in[4];
  const float* proj_w  = (const float*)d_in[5];
  const float* proj_b  = (const float*)d_in[6];
  const float* conv1_w = (const float*)d_in[7];
  const float* conv1_b = (const float*)d_in[8];
  const float* conv2_w = (const float*)d_in[9];
  const float* conv2_b = (const float*)d_in[10];
  float* out = (float*)d_out;

  char* ws = (char*)d_ws;
  size_t off = 0;
  auto alloc = [&](size_t bytes) {
    void* p = ws + off;
    off += (bytes + 255) & ~(size_t)255;
    return p;
  };
  ushort* xn     = (ushort*)alloc((size_t)MTOK * 1024 * 2);
  ushort* qb     = (ushort*)alloc((size_t)MTOK * 1024 * 2);
  ushort* kT     = (ushort*)alloc((size_t)MTOK * 1024 * 2);  // [b,h,d,n]
  ushort* vT     = (ushort*)alloc((size_t)MTOK * 1024 * 2);  // [b,h,e,n]
  ushort* attn_o = (ushort*)alloc((size_t)MTOK * 1024 * 2);
  float*  kvT    = (float*)alloc((size_t)(4 * 16 * 64 * 64 + 4 * 16 * 64) * 4);
  float*  ksum   = kvT + 4 * 16 * 64 * 64;
  ushort* wq = (ushort*)alloc((size_t)3072 * 1024 * 2);
  ushort* wp = (ushort*)alloc((size_t)1024 * 1024 * 2);
  ushort* w1 = (ushort*)alloc((size_t)2048 * 1024 * 2);
  ushort* w2 = (ushort*)alloc((size_t)1024 * 2048 * 2);
  ushort* hid = kT;   // [MTOK][2048] bf16 reuses kT+vT (dead after attention)
  if (off > ws_size) return;

  hipMemsetAsync(kvT, 0, (size_t)(4 * 16 * 64 * 64 + 4 * 16 * 64) * 4, stream);
  f32_to_bf16_k<<<3072, 256, 0, stream>>>(qkv_w, wq, 786432);
  f32_to_bf16_k<<<1024, 256, 0, stream>>>(proj_w, wp, 262144);
  f32_to_bf16_k<<<2048, 256, 0, stream>>>(conv1_w, w1, 524288);
  f32_to_bf16_k<<<2048, 256, 0, stream>>>(conv2_w, w2, 524288);

  // attention branch
  rmsnorm_k<<<MTOK, 256, 0, stream>>>(x, scale1, xn);
  gemm256<0><<<768, 512, 0, stream>>>(xn, wq, qb, nullptr, nullptr, nullptr,
                                      kT, vT, 12, 1024);
  attn_kv_mfma<<<512, 256, 0, stream>>>(kT, vT, kvT, ksum);
  attn_out_mfma<<<1024, 256, 0, stream>>>(qb, kvT, ksum, attn_o);
  gemm256<1><<<256, 512, 0, stream>>>(attn_o, wp, out, proj_b, gamma, x,
                                      nullptr, nullptr, 4, 1024);

  // MLP branch (x1 lives in d_out; conv2 epilogue reads+rewrites it)
  rmsnorm_k<<<MTOK, 256, 0, stream>>>(out, scale2, xn);
  gemm256<2><<<512, 512, 0, stream>>>(xn, w1, hid, conv1_b, nullptr, nullptr,
                                      nullptr, nullptr, 8, 1024);
  gemm256<1><<<256, 512, 0, stream>>>(hid, w2, out, conv2_b, gamma, out,
                                      nullptr, nullptr, 4, 2048);
}

// Round 4
// 581.251 us; speedup vs baseline: 1.0047x; 1.0047x over previous
//
#include <hip/hip_runtime.h>
#include <hip/hip_bf16.h>
#include <math.h>

#define MTOK 16384   // B*N = 4*4096

typedef __attribute__((ext_vector_type(8))) short bf16x8;
typedef __attribute__((ext_vector_type(4))) float f32x4;

__device__ __forceinline__ float bf2f(ushort u) {
  union { unsigned int u; float f; } c; c.u = ((unsigned int)u) << 16; return c.f;
}
__device__ __forceinline__ ushort f2bf(float f) {
  union { float f; unsigned int u; } c; c.f = f;
  unsigned int r = c.u + 0x7fffu + ((c.u >> 16) & 1u);
  return (ushort)(r >> 16);
}

__device__ __forceinline__ void gload_lds16(const void* g, void* l) {
  __builtin_amdgcn_global_load_lds(
      (const __attribute__((address_space(1))) unsigned int*)g,
      (__attribute__((address_space(3))) unsigned int*)l, 16, 0, 0);
}

// ---------------- fp32 -> bf16 convert (weights) ----------------
__global__ __launch_bounds__(256)
void f32_to_bf16_k(const float* __restrict__ in, ushort* __restrict__ out, int n4) {
  int i = blockIdx.x * 256 + threadIdx.x;
  if (i >= n4) return;
  float4 v = *(const float4*)&in[(size_t)i * 4];
  ushort4 o;
  o.x = f2bf(v.x); o.y = f2bf(v.y); o.z = f2bf(v.z); o.w = f2bf(v.w);
  *(ushort4*)&out[(size_t)i * 4] = o;
}

// ---------------- RMSNorm: fp32 in -> bf16 out ----------------
__global__ __launch_bounds__(256)
void rmsnorm_k(const float* __restrict__ x, const float* __restrict__ scale,
               ushort* __restrict__ out) {
  __shared__ float red[4];
  int row = blockIdx.x;
  int t = threadIdx.x;
  const float* xr = x + (size_t)row * 1024;
  float4 v = *(const float4*)&xr[t * 4];
  float s = v.x*v.x + v.y*v.y + v.z*v.z + v.w*v.w;
  #pragma unroll
  for (int off = 32; off > 0; off >>= 1) s += __shfl_xor(s, off);
  if ((t & 63) == 0) red[t >> 6] = s;
  __syncthreads();
  float tot = red[0] + red[1] + red[2] + red[3];
  float rn = (32.0f + 1e-6f) / sqrtf(tot);
  float4 sc = *(const float4*)&scale[t * 4];
  ushort4 o;
  o.x = f2bf(v.x * rn * sc.x);
  o.y = f2bf(v.y * rn * sc.y);
  o.z = f2bf(v.z * rn * sc.z);
  o.w = f2bf(v.w * rn * sc.w);
  *(ushort4*)&out[(size_t)row * 1024 + t * 4] = o;
}

// ======== 256x256 8-phase bf16 MFMA GEMM (m201-style): out[M,F] = A[M,K] @ W[F,K]^T ========
// 8 waves (2M x 4N), BK=64. LDS 128KiB = 2buf x {A,B} x {ks0,ks1} parts of 16KB (256x32).
// Part layout: row-major 64B rows, granule-XOR swizzle (g ^= row&3) applied on the
// pre-swizzled GLOBAL source (staging) and on the ds_read address (both sides).
// 4 phases per K-tile, 16 MFMA each, dual barriers; one part staged per phase
// (7 phases ahead of first read); boundary s_waitcnt vmcnt(6), never 0 mid-loop.
// EPI 0: qkv — q(phi) token-major; k(phi)/v transposed [b,h,ch,n]
// EPI 1: outf32 = resid + gamma*(acc+bias)
// EPI 2: gelu(acc+bias) bf16
template<int EPI>
__global__ __launch_bounds__(512, 2)
void gemm256(const ushort* __restrict__ A, const ushort* __restrict__ W,
             void* __restrict__ outp, const float* __restrict__ bias,
             const float* __restrict__ gamma, const float* __restrict__ resid,
             ushort* __restrict__ kTp, ushort* __restrict__ vTp,
             int nBn, int K) {
  __shared__ ushort lds[65536];   // 128 KiB
  const int tid = threadIdx.x, lane = tid & 63, w = tid >> 6;
  const int wm = w >> 2, wn = w & 3;
  const int frow = lane & 15, kq = lane >> 4;
  const int F = nBn << 8;

  // bijective XCD swizzle (grid % 8 == 0 for all launches here)
  const int swz = ((int)blockIdx.x & 7) * ((int)gridDim.x >> 3) + ((int)blockIdx.x >> 3);
  const int bm = swz / nBn, bn = swz % nBn;
  const int brow = bm << 8, bcol = bn << 8;

  // ---- staging: per-lane pre-swizzled global source ----
  const int rowlane = lane >> 2;                       // 0..15
  const int colg = (((lane & 3) ^ (rowlane & 3)) << 3); // swizzled source granule*8
  const ushort* pa_s = A + (size_t)(brow + w * 16 + rowlane) * K + colg;
  const ushort* pb_s = W + (size_t)(bcol + w * 16 + rowlane) * K + colg;
  const size_t lstr = (size_t)128 * K;                 // second load: +128 rows
  const int sdst = w * 512;                            // wave-uniform LDS base part

  // part codes: 0=(A,ks0) 1=(B,ks0) 2=(A,ks1) 3=(B,ks1)
  // part ushort offsets: A:0 B:16384 ; +ks*8192 ; buf: +b*32768
  auto stage = [&](int part, int T, int buf) {
    const int kshalf = part >> 1;
    const bool isB = part & 1;
    const ushort* s = (isB ? pb_s : pa_s) + T * 64 + kshalf * 32;
    ushort* d = &lds[buf * 32768 + (isB ? 16384 : 0) + kshalf * 8192 + sdst];
    gload_lds16(s, d);            // rows r0..r0+... (lane-linear, HW adds lane*16B)
    gload_lds16(s + lstr, d + 4096);
  };

  // ---- ds_read bases (ushort units), granule-swizzled ----
  const int gsw = ((kq ^ (frow & 3)) << 3);
  const int base_a = (wm * 128 + frow) * 32 + gsw;           // + mi*512 + ks*8192
  const int base_b = 16384 + (wn * 64 + frow) * 32 + gsw;    // + ni*512 + ks*8192

  f32x4 acc[8][4];
  #pragma unroll
  for (int i = 0; i < 8; ++i)
    #pragma unroll
    for (int j = 0; j < 4; ++j) acc[i][j] = (f32x4){0.f, 0.f, 0.f, 0.f};

  bf16x8 ar[4], br[4];
  auto rdA = [&](int bufo, int mh, int ks) {
    #pragma unroll
    for (int mi = 0; mi < 4; ++mi)
      ar[mi] = *(const bf16x8*)&lds[bufo + ks * 8192 + base_a + (mh * 4 + mi) * 512];
  };
  auto rdB = [&](int bufo, int ks) {
    #pragma unroll
    for (int ni = 0; ni < 4; ++ni)
      br[ni] = *(const bf16x8*)&lds[bufo + ks * 8192 + base_b + ni * 512];
  };
  auto mm = [&](int mh) {
    __builtin_amdgcn_s_setprio(1);
    #pragma unroll
    for (int mi = 0; mi < 4; ++mi)
      #pragma unroll
      for (int ni = 0; ni < 4; ++ni)
        acc[mh * 4 + mi][ni] = __builtin_amdgcn_mfma_f32_16x16x32_bf16(
            ar[mi], br[ni], acc[mh * 4 + mi][ni], 0, 0, 0);
    __builtin_amdgcn_s_setprio(0);
  };

  const int NT = K >> 6;
  // prologue: all 4 parts of tile0 -> buf0; parts 0..2 of tile1 -> buf1 (14 loads)
  #pragma unroll
  for (int p = 0; p < 4; ++p) stage(p, 0, 0);
  #pragma unroll
  for (int p = 0; p < 3; ++p) stage(p, 1, 1);
  asm volatile("s_waitcnt vmcnt(6)\ns_barrier" ::: "memory");  // drain tile0's 8

  for (int t = 0; t < NT; ++t) {
    const int bufo = (t & 1) << 15;   // ushort offset of current buf
    // ---- q0: (mh0, ks0); stage P3(t+1) -> other buf ----
    rdA(bufo, 0, 0); rdB(bufo, 0);
    if (t + 1 < NT) stage(3, t + 1, (t + 1) & 1);
    asm volatile("s_barrier" ::: "memory");
    asm volatile("s_waitcnt lgkmcnt(0)" ::: "memory");
    mm(0);
    asm volatile("s_barrier" ::: "memory");
    // ---- q1: (mh1, ks0), reuse br; stage P0(t+2) -> this buf ----
    rdA(bufo, 1, 0);
    if (t + 2 < NT) stage(0, t + 2, t & 1);
    asm volatile("s_barrier" ::: "memory");
    asm volatile("s_waitcnt lgkmcnt(0)" ::: "memory");
    mm(1);
    asm volatile("s_barrier" ::: "memory");
    // ---- q2: (mh0, ks1); stage P1(t+2) ----
    rdA(bufo, 0, 1); rdB(bufo, 1);
    if (t + 2 < NT) stage(1, t + 2, t & 1);
    asm volatile("s_barrier" ::: "memory");
    asm volatile("s_waitcnt lgkmcnt(0)" ::: "memory");
    mm(0);
    asm volatile("s_barrier" ::: "memory");
    // ---- q3: (mh1, ks1), reuse br; stage P2(t+2) ----
    rdA(bufo, 1, 1);
    if (t + 2 < NT) stage(2, t + 2, t & 1);
    asm volatile("s_barrier" ::: "memory");
    asm volatile("s_waitcnt lgkmcnt(0)" ::: "memory");
    mm(1);
    // ---- boundary: counted vmcnt (drains all of tile t+1; keeps t+2's 3 parts) ----
    if (t + 2 < NT)
      asm volatile("s_waitcnt vmcnt(6)\ns_barrier" ::: "memory");
    else if (t + 1 < NT)
      asm volatile("s_waitcnt vmcnt(0)\ns_barrier" ::: "memory");
  }

  // ---- epilogue: row = brow+wm*128+MI*16+kq*4+r, col = bcol+wn*64+ni*16+frow ----
  #pragma unroll
  for (int mi = 0; mi < 8; ++mi) {
    #pragma unroll
    for (int ni = 0; ni < 4; ++ni) {
      int col = bcol + (wn << 6) + (ni << 4) + frow;
      int rbase = brow + (wm << 7) + (mi << 4) + (kq << 2);
      if (EPI == 0) {
        if (col < 1024) {
          #pragma unroll
          for (int r = 0; r < 4; ++r) {
            float v = acc[mi][ni][r];
            ((ushort*)outp)[(size_t)(rbase + r) * 1024 + col] =
                f2bf(__expf(-0.5f * v * v));
          }
        } else {
          bool isk = col < 2048;
          int c = col - (isk ? 1024 : 2048);
          int b = rbase >> 12, n = rbase & 4095;
          ushort4 o;
          #pragma unroll
          for (int r = 0; r < 4; ++r) {
            float v = acc[mi][ni][r];
            if (isk) v = __expf(-0.5f * v * v);
            ((ushort*)&o)[r] = f2bf(v);
          }
          ushort* dst = (isk ? kTp : vTp) +
                        ((size_t)(b * 16 + (c >> 6)) * 64 + (c & 63)) * 4096 + n;
          *(ushort4*)dst = o;
        }
      } else {
        #pragma unroll
        for (int r = 0; r < 4; ++r) {
          int row = rbase + r;
          float v = acc[mi][ni][r];
          size_t idx = (size_t)row * F + col;
          if (EPI == 1) {
            ((float*)outp)[idx] = resid[idx] + gamma[col] * (v + bias[col]);
          } else {
            float t2 = v + bias[col];
            ((ushort*)outp)[idx] =
                f2bf(0.5f * t2 * (1.0f + erff(t2 * 0.70710678118f)));
          }
        }
      }
    }
  }
}

// ---------------- kvT[b,h,e,d] = sum_n v[n,e]*k[n,d]  (MFMA, split-K) ----------------
__global__ __launch_bounds__(256)
void attn_kv_mfma(const ushort* __restrict__ kT, const ushort* __restrict__ vT,
                  float* __restrict__ kvT, float* __restrict__ ksum) {
  __shared__ float red[4][4096];
  int bi = blockIdx.x;
  int ksl = bi & 7, h = (bi >> 3) & 15, b = bi >> 7;
  int tid = threadIdx.x, lane = tid & 63, w = tid >> 6;
  int frow = lane & 15, kq = lane >> 4;
  const size_t bh = (size_t)(b * 16 + h) * 64;
  const ushort* vb = vT + bh * 4096;
  const ushort* kb = kT + bh * 4096;
  int tk0 = ksl * 512 + w * 128;

  f32x4 acc[4][4];
  #pragma unroll
  for (int i = 0; i < 4; ++i)
    #pragma unroll
    for (int j = 0; j < 4; ++j) acc[i][j] = (f32x4){0.f, 0.f, 0.f, 0.f};
  float kpart[4] = {0.f, 0.f, 0.f, 0.f};

  #pragma unroll
  for (int kstep = 0; kstep < 4; ++kstep) {
    int tok = tk0 + kstep * 32 + kq * 8;
    bf16x8 af[4], bfr[4];
    #pragma unroll
    for (int mi = 0; mi < 4; ++mi)
      af[mi] = *(const bf16x8*)&vb[(size_t)(mi * 16 + frow) * 4096 + tok];
    #pragma unroll
    for (int ni = 0; ni < 4; ++ni) {
      bfr[ni] = *(const bf16x8*)&kb[(size_t)(ni * 16 + frow) * 4096 + tok];
      #pragma unroll
      for (int j = 0; j < 8; ++j) kpart[ni] += bf2f((ushort)bfr[ni][j]);
    }
    #pragma unroll
    for (int mi = 0; mi < 4; ++mi)
      #pragma unroll
      for (int ni = 0; ni < 4; ++ni)
        acc[mi][ni] = __builtin_amdgcn_mfma_f32_16x16x32_bf16(
            af[mi], bfr[ni], acc[mi][ni], 0, 0, 0);
  }

  #pragma unroll
  for (int ni = 0; ni < 4; ++ni) {
    kpart[ni] += __shfl_xor(kpart[ni], 16);
    kpart[ni] += __shfl_xor(kpart[ni], 32);
  }
  if (lane < 16) {
    #pragma unroll
    for (int ni = 0; ni < 4; ++ni)
      atomicAdd(&ksum[(b * 16 + h) * 64 + ni * 16 + frow], kpart[ni]);
  }

  #pragma unroll
  for (int mi = 0; mi < 4; ++mi)
    #pragma unroll
    for (int ni = 0; ni < 4; ++ni)
      #pragma unroll
      for (int r = 0; r < 4; ++r)
        red[w][(mi * 16 + kq * 4 + r) * 64 + ni * 16 + frow] = acc[mi][ni][r];
  __syncthreads();
  float* kvg = kvT + (size_t)(b * 16 + h) * 4096;
  for (int i = tid; i < 4096; i += 256) {
    float s = red[0][i] + red[1][i] + red[2][i] + red[3][i];
    atomicAdd(&kvg[i], s);
  }
}

// ---------------- out[n,e] = z * sum_d q[n,d]*kvT[e,d]  (MFMA) ----------------
__global__ __launch_bounds__(256)
void attn_out_mfma(const ushort* __restrict__ qb, const float* __restrict__ kvT,
                   const float* __restrict__ ksum, ushort* __restrict__ ao) {
  __shared__ ushort skv[64 * 72];
  __shared__ float sks[64];
  int bi = blockIdx.x;
  int c = bi & 15, h = (bi >> 4) & 15, b = bi >> 8;
  int tid = threadIdx.x, lane = tid & 63, w = tid >> 6;
  int frow = lane & 15, kq = lane >> 4;
  const float* kvg = kvT + (size_t)(b * 16 + h) * 4096;
  for (int i = tid; i < 4096; i += 256)
    skv[(i >> 6) * 72 + (i & 63)] = f2bf(kvg[i]);
  if (tid < 64) sks[tid] = ksum[(b * 16 + h) * 64 + tid];
  __syncthreads();

  int m0 = b * 4096 + c * 256 + w * 64;
  f32x4 acc[4][4];
  #pragma unroll
  for (int i = 0; i < 4; ++i)
    #pragma unroll
    for (int j = 0; j < 4; ++j) acc[i][j] = (f32x4){0.f, 0.f, 0.f, 0.f};
  float dp[4] = {0.f, 0.f, 0.f, 0.f};

  #pragma unroll
  for (int kst = 0; kst < 2; ++kst) {
    int d0 = kst * 32 + kq * 8;
    bf16x8 af[4], bfr[4];
    #pragma unroll
    for (int mi = 0; mi < 4; ++mi)
      af[mi] = *(const bf16x8*)&qb[(size_t)(m0 + mi * 16 + frow) * 1024 + h * 64 + d0];
    #pragma unroll
    for (int ni = 0; ni < 4; ++ni)
      bfr[ni] = *(const bf16x8*)&skv[(ni * 16 + frow) * 72 + d0];
    #pragma unroll
    for (int mi = 0; mi < 4; ++mi) {
      float s = 0.f;
      #pragma unroll
      for (int j = 0; j < 8; ++j) s += bf2f((ushort)af[mi][j]) * sks[d0 + j];
      dp[mi] += s;
    }
    #pragma unroll
    for (int mi = 0; mi < 4; ++mi)
      #pragma unroll
      for (int ni = 0; ni < 4; ++ni)
        acc[mi][ni] = __builtin_amdgcn_mfma_f32_16x16x32_bf16(
            af[mi], bfr[ni], acc[mi][ni], 0, 0, 0);
  }

  #pragma unroll
  for (int mi = 0; mi < 4; ++mi) {
    dp[mi] += __shfl_xor(dp[mi], 16);
    dp[mi] += __shfl_xor(dp[mi], 32);
  }

  #pragma unroll
  for (int mi = 0; mi < 4; ++mi)
    #pragma unroll
    for (int ni = 0; ni < 4; ++ni)
      #pragma unroll
      for (int r = 0; r < 4; ++r) {
        float dotv = __shfl(dp[mi], (kq << 2) + r);
        float z = 1.f / (dotv + 1e-6f);
        int mrow = m0 + mi * 16 + kq * 4 + r;
        ao[(size_t)mrow * 1024 + h * 64 + ni * 16 + frow] =
            f2bf(acc[mi][ni][r] * z);
      }
}

extern "C" void kernel_launch(void* const* d_in, const int* in_sizes, int n_in,
                              void* d_out, int out_size, void* d_ws, size_t ws_size,
                              hipStream_t stream) {
  const float* x       = (const float*)d_in[0];
  const float* scale1  = (const float*)d_in[1];
  const float* scale2  = (const float*)d_in[2];
  const float* gamma   = (const float*)d_in[3];
  const float* qkv_w   = (const float*)d_in[4];
  const float* proj_w  = (const float*)d_in[5];
  const float* proj_b  = (const float*)d_in[6];
  const float* conv1_w = (const float*)d_in[7];
  const float* conv1_b = (const float*)d_in[8];
  const float* conv2_w = (const float*)d_in[9];
  const float* conv2_b = (const float*)d_in[10];
  float* out = (float*)d_out;

  char* ws = (char*)d_ws;
  size_t off = 0;
  auto alloc = [&](size_t bytes) {
    void* p = ws + off;
    off += (bytes + 255) & ~(size_t)255;
    return p;
  };
  ushort* xn     = (ushort*)alloc((size_t)MTOK * 1024 * 2);
  ushort* qb     = (ushort*)alloc((size_t)MTOK * 1024 * 2);
  ushort* kT     = (ushort*)alloc((size_t)MTOK * 1024 * 2);  // [b,h,d,n]
  ushort* vT     = (ushort*)alloc((size_t)MTOK * 1024 * 2);  // [b,h,e,n]
  ushort* attn_o = (ushort*)alloc((size_t)MTOK * 1024 * 2);
  float*  kvT    = (float*)alloc((size_t)(4 * 16 * 64 * 64 + 4 * 16 * 64) * 4);
  float*  ksum   = kvT + 4 * 16 * 64 * 64;
  ushort* wq = (ushort*)alloc((size_t)3072 * 1024 * 2);
  ushort* wp = (ushort*)alloc((size_t)1024 * 1024 * 2);
  ushort* w1 = (ushort*)alloc((size_t)2048 * 1024 * 2);
  ushort* w2 = (ushort*)alloc((size_t)1024 * 2048 * 2);
  ushort* hid = kT;   // [MTOK][2048] bf16 reuses kT+vT (dead after attention)
  if (off > ws_size) return;

  hipMemsetAsync(kvT, 0, (size_t)(4 * 16 * 64 * 64 + 4 * 16 * 64) * 4, stream);
  f32_to_bf16_k<<<3072, 256, 0, stream>>>(qkv_w, wq, 786432);
  f32_to_bf16_k<<<1024, 256, 0, stream>>>(proj_w, wp, 262144);
  f32_to_bf16_k<<<2048, 256, 0, stream>>>(conv1_w, w1, 524288);
  f32_to_bf16_k<<<2048, 256, 0, stream>>>(conv2_w, w2, 524288);

  // attention branch
  rmsnorm_k<<<MTOK, 256, 0, stream>>>(x, scale1, xn);
  gemm256<0><<<768, 512, 0, stream>>>(xn, wq, qb, nullptr, nullptr, nullptr,
                                      kT, vT, 12, 1024);
  attn_kv_mfma<<<512, 256, 0, stream>>>(kT, vT, kvT, ksum);
  attn_out_mfma<<<1024, 256, 0, stream>>>(qb, kvT, ksum, attn_o);
  gemm256<1><<<256, 512, 0, stream>>>(attn_o, wp, out, proj_b, gamma, x,
                                      nullptr, nullptr, 4, 1024);

  // MLP branch (x1 lives in d_out; conv2 epilogue reads+rewrites it)
  rmsnorm_k<<<MTOK, 256, 0, stream>>>(out, scale2, xn);
  gemm256<2><<<512, 512, 0, stream>>>(xn, w1, hid, conv1_b, nullptr, nullptr,
                                      nullptr, nullptr, 8, 1024);
  gemm256<1><<<256, 512, 0, stream>>>(hid, w2, out, conv2_b, gamma, out,
                                      nullptr, nullptr, 4, 2048);
}

// Round 5
// 495.115 us; speedup vs baseline: 1.1795x; 1.1740x over previous
//
#include <hip/hip_runtime.h>
#include <hip/hip_bf16.h>
#include <math.h>

#define MTOK 16384   // B*N = 4*4096

typedef __attribute__((ext_vector_type(8))) short bf16x8;
typedef __attribute__((ext_vector_type(4))) float f32x4;

__device__ __forceinline__ float bf2f(ushort u) {
  union { unsigned int u; float f; } c; c.u = ((unsigned int)u) << 16; return c.f;
}
__device__ __forceinline__ ushort f2bf(float f) {
  union { float f; unsigned int u; } c; c.f = f;
  unsigned int r = c.u + 0x7fffu + ((c.u >> 16) & 1u);
  return (ushort)(r >> 16);
}

__device__ __forceinline__ void gload_lds16(const void* g, void* l) {
  __builtin_amdgcn_global_load_lds(
      (const __attribute__((address_space(1))) unsigned int*)g,
      (__attribute__((address_space(3))) unsigned int*)l, 16, 0, 0);
}

// ---------------- fp32 -> bf16 convert (weights) ----------------
__global__ __launch_bounds__(256)
void f32_to_bf16_k(const float* __restrict__ in, ushort* __restrict__ out, int n4) {
  int i = blockIdx.x * 256 + threadIdx.x;
  if (i >= n4) return;
  float4 v = *(const float4*)&in[(size_t)i * 4];
  ushort4 o;
  o.x = f2bf(v.x); o.y = f2bf(v.y); o.z = f2bf(v.z); o.w = f2bf(v.w);
  *(ushort4*)&out[(size_t)i * 4] = o;
}

// ---------------- RMSNorm: fp32 in -> bf16 out ----------------
__global__ __launch_bounds__(256)
void rmsnorm_k(const float* __restrict__ x, const float* __restrict__ scale,
               ushort* __restrict__ out) {
  __shared__ float red[4];
  int row = blockIdx.x;
  int t = threadIdx.x;
  const float* xr = x + (size_t)row * 1024;
  float4 v = *(const float4*)&xr[t * 4];
  float s = v.x*v.x + v.y*v.y + v.z*v.z + v.w*v.w;
  #pragma unroll
  for (int off = 32; off > 0; off >>= 1) s += __shfl_xor(s, off);
  if ((t & 63) == 0) red[t >> 6] = s;
  __syncthreads();
  float tot = red[0] + red[1] + red[2] + red[3];
  float rn = (32.0f + 1e-6f) / sqrtf(tot);
  float4 sc = *(const float4*)&scale[t * 4];
  ushort4 o;
  o.x = f2bf(v.x * rn * sc.x);
  o.y = f2bf(v.y * rn * sc.y);
  o.z = f2bf(v.z * rn * sc.z);
  o.w = f2bf(v.w * rn * sc.w);
  *(ushort4*)&out[(size_t)row * 1024 + t * 4] = o;
}

// ---------------- bf16 MFMA GEMM: out[M,F] = A[M,K] @ W[F,K]^T ----------------
// R2 structure (128x128 tile, BK=32, 4 waves, verified 644 TF) + minimal 2-phase
// double-buffer (T3-minimum): STAGE(buf^1, t+1) issued BEFORE the ds_read+MFMA of
// tile t; one __syncthreads (vmcnt0+lgkmcnt0+barrier) per tile. LDS 32KB.
// EPI 0: qkv — q(phi) token-major; k(phi)/v transposed [b,h,ch,n]
// EPI 1: outf32 = resid + gamma*(acc+bias)
// EPI 2: gelu(acc+bias) bf16
template<int EPI>
__global__ __launch_bounds__(256, 2)
void gemm_bt(const ushort* __restrict__ A, const ushort* __restrict__ W,
             void* __restrict__ outp, const float* __restrict__ bias,
             const float* __restrict__ gamma, const float* __restrict__ resid,
             ushort* __restrict__ kTp, ushort* __restrict__ vTp,
             int M, int F, int K) {
  __shared__ ushort lA[2][128 * 32];
  __shared__ ushort lB[2][128 * 32];
  const int tid = threadIdx.x;
  const int lane = tid & 63;
  const int w = tid >> 6;
  const int nBn = F >> 7;
  const int bm = blockIdx.x / nBn;
  const int bn = blockIdx.x % nBn;
  const int brow = bm << 7, bcol = bn << 7;
  const int wr = w >> 1, wc = w & 1;

  // staging: wave w covers tile rows [w*16, w*16+16) (inst0) and +64 (inst1),
  // lane -> row = w*16 + lane/4, kc_pos = lane&3. LDS dst lane-linear;
  // kc-chunk XOR swizzle on the global SOURCE (both-sides, rule #21).
  const int srow = (w << 4) + (lane >> 2);
  const int key = (srow >> 1) & 3;
  const int kcsrc = (lane & 3) ^ key;
  const ushort* gA0 = A + (size_t)(brow + srow) * K + kcsrc * 8;
  const ushort* gA1 = gA0 + (size_t)64 * K;
  const ushort* gB0 = W + (size_t)(bcol + srow) * K + kcsrc * 8;
  const ushort* gB1 = gB0 + (size_t)64 * K;

  auto stage = [&](int bf, int k0) {
    gload_lds16(gA0 + k0, &lA[bf][w * 512]);
    gload_lds16(gA1 + k0, &lA[bf][2048 + w * 512]);
    gload_lds16(gB0 + k0, &lB[bf][w * 512]);
    gload_lds16(gB1 + k0, &lB[bf][2048 + w * 512]);
  };

  const int frow = lane & 15;
  const int kq = lane >> 4;

  f32x4 acc[4][4];
  #pragma unroll
  for (int i = 0; i < 4; ++i)
    #pragma unroll
    for (int j = 0; j < 4; ++j) acc[i][j] = (f32x4){0.f, 0.f, 0.f, 0.f};

  stage(0, 0);
  __syncthreads();

  int buf = 0;
  for (int k0 = 0; k0 < K; k0 += 32, buf ^= 1) {
    // issue next tile's stage FIRST — its latency hides under this tile's MFMA
    if (k0 + 32 < K) stage(buf ^ 1, k0 + 32);

    bf16x8 af[4], bfr[4];
    #pragma unroll
    for (int mi = 0; mi < 4; ++mi) {
      int row = (wr << 6) + (mi << 4) + frow;
      int off = (row << 5) + ((kq ^ ((row >> 1) & 3)) << 3);
      af[mi] = *(const bf16x8*)&lA[buf][off];
    }
    #pragma unroll
    for (int ni = 0; ni < 4; ++ni) {
      int row = (wc << 6) + (ni << 4) + frow;
      int off = (row << 5) + ((kq ^ ((row >> 1) & 3)) << 3);
      bfr[ni] = *(const bf16x8*)&lB[buf][off];
    }
    #pragma unroll
    for (int mi = 0; mi < 4; ++mi)
      #pragma unroll
      for (int ni = 0; ni < 4; ++ni)
        acc[mi][ni] = __builtin_amdgcn_mfma_f32_16x16x32_bf16(
            af[mi], bfr[ni], acc[mi][ni], 0, 0, 0);
    __syncthreads();   // drains stage(t+1) + this tile's ds_reads
  }

  // epilogue: C row = (lane>>4)*4+r, col = lane&15 (m89-verified layout)
  #pragma unroll
  for (int mi = 0; mi < 4; ++mi) {
    #pragma unroll
    for (int ni = 0; ni < 4; ++ni) {
      int col = bcol + (wc << 6) + (ni << 4) + frow;
      int rbase = brow + (wr << 6) + (mi << 4) + (kq << 2);
      if (EPI == 0) {
        if (col < 1024) {
          #pragma unroll
          for (int r = 0; r < 4; ++r) {
            float v = acc[mi][ni][r];
            ((ushort*)outp)[(size_t)(rbase + r) * 1024 + col] =
                f2bf(__expf(-0.5f * v * v));
          }
        } else {
          bool isk = col < 2048;
          int c = col - (isk ? 1024 : 2048);
          int b = rbase >> 12, n = rbase & 4095;
          ushort4 o;
          #pragma unroll
          for (int r = 0; r < 4; ++r) {
            float v = acc[mi][ni][r];
            if (isk) v = __expf(-0.5f * v * v);
            ((ushort*)&o)[r] = f2bf(v);
          }
          ushort* dst = (isk ? kTp : vTp) +
                        ((size_t)(b * 16 + (c >> 6)) * 64 + (c & 63)) * 4096 + n;
          *(ushort4*)dst = o;
        }
      } else {
        #pragma unroll
        for (int r = 0; r < 4; ++r) {
          int row = rbase + r;
          float v = acc[mi][ni][r];
          size_t idx = (size_t)row * F + col;
          if (EPI == 1) {
            ((float*)outp)[idx] = resid[idx] + gamma[col] * (v + bias[col]);
          } else {
            float t2 = v + bias[col];
            ((ushort*)outp)[idx] =
                f2bf(0.5f * t2 * (1.0f + erff(t2 * 0.70710678118f)));
          }
        }
      }
    }
  }
}

// ---------------- kvT[b,h,e,d] = sum_n v[n,e]*k[n,d]  (MFMA, split-K) ----------------
__global__ __launch_bounds__(256)
void attn_kv_mfma(const ushort* __restrict__ kT, const ushort* __restrict__ vT,
                  float* __restrict__ kvT, float* __restrict__ ksum) {
  __shared__ float red[4][4096];
  int bi = blockIdx.x;
  int ksl = bi & 7, h = (bi >> 3) & 15, b = bi >> 7;
  int tid = threadIdx.x, lane = tid & 63, w = tid >> 6;
  int frow = lane & 15, kq = lane >> 4;
  const size_t bh = (size_t)(b * 16 + h) * 64;
  const ushort* vb = vT + bh * 4096;
  const ushort* kb = kT + bh * 4096;
  int tk0 = ksl * 512 + w * 128;

  f32x4 acc[4][4];
  #pragma unroll
  for (int i = 0; i < 4; ++i)
    #pragma unroll
    for (int j = 0; j < 4; ++j) acc[i][j] = (f32x4){0.f, 0.f, 0.f, 0.f};
  float kpart[4] = {0.f, 0.f, 0.f, 0.f};

  #pragma unroll
  for (int kstep = 0; kstep < 4; ++kstep) {
    int tok = tk0 + kstep * 32 + kq * 8;
    bf16x8 af[4], bfr[4];
    #pragma unroll
    for (int mi = 0; mi < 4; ++mi)
      af[mi] = *(const bf16x8*)&vb[(size_t)(mi * 16 + frow) * 4096 + tok];
    #pragma unroll
    for (int ni = 0; ni < 4; ++ni) {
      bfr[ni] = *(const bf16x8*)&kb[(size_t)(ni * 16 + frow) * 4096 + tok];
      #pragma unroll
      for (int j = 0; j < 8; ++j) kpart[ni] += bf2f((ushort)bfr[ni][j]);
    }
    #pragma unroll
    for (int mi = 0; mi < 4; ++mi)
      #pragma unroll
      for (int ni = 0; ni < 4; ++ni)
        acc[mi][ni] = __builtin_amdgcn_mfma_f32_16x16x32_bf16(
            af[mi], bfr[ni], acc[mi][ni], 0, 0, 0);
  }

  #pragma unroll
  for (int ni = 0; ni < 4; ++ni) {
    kpart[ni] += __shfl_xor(kpart[ni], 16);
    kpart[ni] += __shfl_xor(kpart[ni], 32);
  }
  if (lane < 16) {
    #pragma unroll
    for (int ni = 0; ni < 4; ++ni)
      atomicAdd(&ksum[(b * 16 + h) * 64 + ni * 16 + frow], kpart[ni]);
  }

  #pragma unroll
  for (int mi = 0; mi < 4; ++mi)
    #pragma unroll
    for (int ni = 0; ni < 4; ++ni)
      #pragma unroll
      for (int r = 0; r < 4; ++r)
        red[w][(mi * 16 + kq * 4 + r) * 64 + ni * 16 + frow] = acc[mi][ni][r];
  __syncthreads();
  float* kvg = kvT + (size_t)(b * 16 + h) * 4096;
  for (int i = tid; i < 4096; i += 256) {
    float s = red[0][i] + red[1][i] + red[2][i] + red[3][i];
    atomicAdd(&kvg[i], s);
  }
}

// ---------------- out[n,e] = z * sum_d q[n,d]*kvT[e,d]  (MFMA) ----------------
__global__ __launch_bounds__(256)
void attn_out_mfma(const ushort* __restrict__ qb, const float* __restrict__ kvT,
                   const float* __restrict__ ksum, ushort* __restrict__ ao) {
  __shared__ ushort skv[64 * 72];
  __shared__ float sks[64];
  int bi = blockIdx.x;
  int c = bi & 15, h = (bi >> 4) & 15, b = bi >> 8;
  int tid = threadIdx.x, lane = tid & 63, w = tid >> 6;
  int frow = lane & 15, kq = lane >> 4;
  const float* kvg = kvT + (size_t)(b * 16 + h) * 4096;
  for (int i = tid; i < 4096; i += 256)
    skv[(i >> 6) * 72 + (i & 63)] = f2bf(kvg[i]);
  if (tid < 64) sks[tid] = ksum[(b * 16 + h) * 64 + tid];
  __syncthreads();

  int m0 = b * 4096 + c * 256 + w * 64;
  f32x4 acc[4][4];
  #pragma unroll
  for (int i = 0; i < 4; ++i)
    #pragma unroll
    for (int j = 0; j < 4; ++j) acc[i][j] = (f32x4){0.f, 0.f, 0.f, 0.f};
  float dp[4] = {0.f, 0.f, 0.f, 0.f};

  #pragma unroll
  for (int kst = 0; kst < 2; ++kst) {
    int d0 = kst * 32 + kq * 8;
    bf16x8 af[4], bfr[4];
    #pragma unroll
    for (int mi = 0; mi < 4; ++mi)
      af[mi] = *(const bf16x8*)&qb[(size_t)(m0 + mi * 16 + frow) * 1024 + h * 64 + d0];
    #pragma unroll
    for (int ni = 0; ni < 4; ++ni)
      bfr[ni] = *(const bf16x8*)&skv[(ni * 16 + frow) * 72 + d0];
    #pragma unroll
    for (int mi = 0; mi < 4; ++mi) {
      float s = 0.f;
      #pragma unroll
      for (int j = 0; j < 8; ++j) s += bf2f((ushort)af[mi][j]) * sks[d0 + j];
      dp[mi] += s;
    }
    #pragma unroll
    for (int mi = 0; mi < 4; ++mi)
      #pragma unroll
      for (int ni = 0; ni < 4; ++ni)
        acc[mi][ni] = __builtin_amdgcn_mfma_f32_16x16x32_bf16(
            af[mi], bfr[ni], acc[mi][ni], 0, 0, 0);
  }

  #pragma unroll
  for (int mi = 0; mi < 4; ++mi) {
    dp[mi] += __shfl_xor(dp[mi], 16);
    dp[mi] += __shfl_xor(dp[mi], 32);
  }

  #pragma unroll
  for (int mi = 0; mi < 4; ++mi)
    #pragma unroll
    for (int ni = 0; ni < 4; ++ni)
      #pragma unroll
      for (int r = 0; r < 4; ++r) {
        float dotv = __shfl(dp[mi], (kq << 2) + r);
        float z = 1.f / (dotv + 1e-6f);
        int mrow = m0 + mi * 16 + kq * 4 + r;
        ao[(size_t)mrow * 1024 + h * 64 + ni * 16 + frow] =
            f2bf(acc[mi][ni][r] * z);
      }
}

extern "C" void kernel_launch(void* const* d_in, const int* in_sizes, int n_in,
                              void* d_out, int out_size, void* d_ws, size_t ws_size,
                              hipStream_t stream) {
  const float* x       = (const float*)d_in[0];
  const float* scale1  = (const float*)d_in[1];
  const float* scale2  = (const float*)d_in[2];
  const float* gamma   = (const float*)d_in[3];
  const float* qkv_w   = (const float*)d_in[4];
  const float* proj_w  = (const float*)d_in[5];
  const float* proj_b  = (const float*)d_in[6];
  const float* conv1_w = (const float*)d_in[7];
  const float* conv1_b = (const float*)d_in[8];
  const float* conv2_w = (const float*)d_in[9];
  const float* conv2_b = (const float*)d_in[10];
  float* out = (float*)d_out;

  char* ws = (char*)d_ws;
  size_t off = 0;
  auto alloc = [&](size_t bytes) {
    void* p = ws + off;
    off += (bytes + 255) & ~(size_t)255;
    return p;
  };
  ushort* xn     = (ushort*)alloc((size_t)MTOK * 1024 * 2);
  ushort* qb     = (ushort*)alloc((size_t)MTOK * 1024 * 2);
  ushort* kT     = (ushort*)alloc((size_t)MTOK * 1024 * 2);  // [b,h,d,n]
  ushort* vT     = (ushort*)alloc((size_t)MTOK * 1024 * 2);  // [b,h,e,n]
  ushort* attn_o = (ushort*)alloc((size_t)MTOK * 1024 * 2);
  float*  kvT    = (float*)alloc((size_t)(4 * 16 * 64 * 64 + 4 * 16 * 64) * 4);
  float*  ksum   = kvT + 4 * 16 * 64 * 64;
  ushort* wq = (ushort*)alloc((size_t)3072 * 1024 * 2);
  ushort* wp = (ushort*)alloc((size_t)1024 * 1024 * 2);
  ushort* w1 = (ushort*)alloc((size_t)2048 * 1024 * 2);
  ushort* w2 = (ushort*)alloc((size_t)1024 * 2048 * 2);
  ushort* hid = kT;   // [MTOK][2048] bf16 reuses kT+vT (dead after attention)
  if (off > ws_size) return;

  hipMemsetAsync(kvT, 0, (size_t)(4 * 16 * 64 * 64 + 4 * 16 * 64) * 4, stream);
  f32_to_bf16_k<<<3072, 256, 0, stream>>>(qkv_w, wq, 786432);
  f32_to_bf16_k<<<1024, 256, 0, stream>>>(proj_w, wp, 262144);
  f32_to_bf16_k<<<2048, 256, 0, stream>>>(conv1_w, w1, 524288);
  f32_to_bf16_k<<<2048, 256, 0, stream>>>(conv2_w, w2, 524288);

  // attention branch
  rmsnorm_k<<<MTOK, 256, 0, stream>>>(x, scale1, xn);
  gemm_bt<0><<<128 * 24, 256, 0, stream>>>(xn, wq, qb, nullptr, nullptr, nullptr,
                                           kT, vT, MTOK, 3072, 1024);
  attn_kv_mfma<<<512, 256, 0, stream>>>(kT, vT, kvT, ksum);
  attn_out_mfma<<<1024, 256, 0, stream>>>(qb, kvT, ksum, attn_o);
  gemm_bt<1><<<128 * 8, 256, 0, stream>>>(attn_o, wp, out, proj_b, gamma, x,
                                          nullptr, nullptr, MTOK, 1024, 1024);

  // MLP branch (x1 lives in d_out; conv2 epilogue reads+rewrites it)
  rmsnorm_k<<<MTOK, 256, 0, stream>>>(out, scale2, xn);
  gemm_bt<2><<<128 * 16, 256, 0, stream>>>(xn, w1, hid, conv1_b, nullptr, nullptr,
                                           nullptr, nullptr, MTOK, 2048, 1024);
  gemm_bt<1><<<128 * 8, 256, 0, stream>>>(hid, w2, out, conv2_b, gamma, out,
                                          nullptr, nullptr, MTOK, 1024, 2048);
}

// Round 6
// 463.415 us; speedup vs baseline: 1.2602x; 1.0684x over previous
//
#include <hip/hip_runtime.h>
#include <hip/hip_bf16.h>
#include <math.h>

#define MTOK 16384   // B*N = 4*4096

typedef __attribute__((ext_vector_type(8))) short bf16x8;
typedef __attribute__((ext_vector_type(4))) float f32x4;

__device__ __forceinline__ float bf2f(ushort u) {
  union { unsigned int u; float f; } c; c.u = ((unsigned int)u) << 16; return c.f;
}
__device__ __forceinline__ ushort f2bf(float f) {
  union { float f; unsigned int u; } c; c.f = f;
  unsigned int r = c.u + 0x7fffu + ((c.u >> 16) & 1u);
  return (ushort)(r >> 16);
}

__device__ __forceinline__ void gload_lds16(const void* g, void* l) {
  __builtin_amdgcn_global_load_lds(
      (const __attribute__((address_space(1))) unsigned int*)g,
      (__attribute__((address_space(3))) unsigned int*)l, 16, 0, 0);
}

// ---------------- fp32 -> bf16 convert (weights) ----------------
__global__ __launch_bounds__(256)
void f32_to_bf16_k(const float* __restrict__ in, ushort* __restrict__ out, int n4) {
  int i = blockIdx.x * 256 + threadIdx.x;
  if (i >= n4) return;
  float4 v = *(const float4*)&in[(size_t)i * 4];
  ushort4 o;
  o.x = f2bf(v.x); o.y = f2bf(v.y); o.z = f2bf(v.z); o.w = f2bf(v.w);
  *(ushort4*)&out[(size_t)i * 4] = o;
}

// fp32 -> bf16 with per-ROW scale (folds gamma into weight rows): row = idx/K_in
__global__ __launch_bounds__(256)
void f32_to_bf16_rs_k(const float* __restrict__ in, ushort* __restrict__ out,
                      int n4, const float* __restrict__ rs, int K_in) {
  int i = blockIdx.x * 256 + threadIdx.x;
  if (i >= n4) return;
  float g = rs[(i * 4) / K_in];   // K_in % 4 == 0 -> all 4 elems same row
  float4 v = *(const float4*)&in[(size_t)i * 4];
  ushort4 o;
  o.x = f2bf(v.x * g); o.y = f2bf(v.y * g); o.z = f2bf(v.z * g); o.w = f2bf(v.w * g);
  *(ushort4*)&out[(size_t)i * 4] = o;
}

// gb[c] = gamma[c] * bias[c]  (1024 elems)
__global__ __launch_bounds__(256)
void gbias_k(const float* __restrict__ gamma, const float* __restrict__ bias,
             float* __restrict__ gb, int n) {
  int i = blockIdx.x * 256 + threadIdx.x;
  if (i < n) gb[i] = gamma[i] * bias[i];
}

// ---------------- RMSNorm: fp32 in -> bf16 out ----------------
__global__ __launch_bounds__(256)
void rmsnorm_k(const float* __restrict__ x, const float* __restrict__ scale,
               ushort* __restrict__ out) {
  __shared__ float red[4];
  int row = blockIdx.x;
  int t = threadIdx.x;
  const float* xr = x + (size_t)row * 1024;
  float4 v = *(const float4*)&xr[t * 4];
  float s = v.x*v.x + v.y*v.y + v.z*v.z + v.w*v.w;
  #pragma unroll
  for (int off = 32; off > 0; off >>= 1) s += __shfl_xor(s, off);
  if ((t & 63) == 0) red[t >> 6] = s;
  __syncthreads();
  float tot = red[0] + red[1] + red[2] + red[3];
  float rn = (32.0f + 1e-6f) / sqrtf(tot);
  float4 sc = *(const float4*)&scale[t * 4];
  ushort4 o;
  o.x = f2bf(v.x * rn * sc.x);
  o.y = f2bf(v.y * rn * sc.y);
  o.z = f2bf(v.z * rn * sc.z);
  o.w = f2bf(v.w * rn * sc.w);
  *(ushort4*)&out[(size_t)row * 1024 + t * 4] = o;
}

// ---------------- bf16 MFMA GEMM: out[M,F] = A[M,K] @ W[F,K]^T ----------------
// 128x128 tile, BK=32, 4 waves, 2-phase LDS dbuf (stage t+1 before MFMA of t),
// kc-chunk XOR swizzle on global SOURCE + ds_read (both-sides, rule #21),
// XCD-chunked bijective block swizzle (T1; grid % 8 == 0 for all launches).
// EPI 0: qkv — q(phi) token-major; k(phi)/v transposed [b,h,ch,n]
// EPI 1: outf32 = resid + acc + gb[col]   (gamma pre-folded into W rows and gb)
// EPI 2: gelu(acc+bias) bf16 (tanh approx)
template<int EPI>
__global__ __launch_bounds__(256, 2)
void gemm_bt(const ushort* __restrict__ A, const ushort* __restrict__ W,
             void* __restrict__ outp, const float* __restrict__ bias,
             const float* __restrict__ resid,
             ushort* __restrict__ kTp, ushort* __restrict__ vTp,
             int M, int F, int K) {
  __shared__ ushort lA[2][128 * 32];
  __shared__ ushort lB[2][128 * 32];
  const int tid = threadIdx.x;
  const int lane = tid & 63;
  const int w = tid >> 6;
  const int nBn = F >> 7;
  // T1: XCD gets a contiguous bm-major chunk of tiles (bijective: grid%8==0)
  const int cpx = (int)gridDim.x >> 3;
  const int tile = ((int)blockIdx.x & 7) * cpx + ((int)blockIdx.x >> 3);
  const int bm = tile / nBn;
  const int bn = tile % nBn;
  const int brow = bm << 7, bcol = bn << 7;
  const int wr = w >> 1, wc = w & 1;

  const int srow = (w << 4) + (lane >> 2);
  const int key = (srow >> 1) & 3;
  const int kcsrc = (lane & 3) ^ key;
  const ushort* gA0 = A + (size_t)(brow + srow) * K + kcsrc * 8;
  const ushort* gA1 = gA0 + (size_t)64 * K;
  const ushort* gB0 = W + (size_t)(bcol + srow) * K + kcsrc * 8;
  const ushort* gB1 = gB0 + (size_t)64 * K;

  auto stage = [&](int bf, int k0) {
    gload_lds16(gA0 + k0, &lA[bf][w * 512]);
    gload_lds16(gA1 + k0, &lA[bf][2048 + w * 512]);
    gload_lds16(gB0 + k0, &lB[bf][w * 512]);
    gload_lds16(gB1 + k0, &lB[bf][2048 + w * 512]);
  };

  const int frow = lane & 15;
  const int kq = lane >> 4;

  f32x4 acc[4][4];
  #pragma unroll
  for (int i = 0; i < 4; ++i)
    #pragma unroll
    for (int j = 0; j < 4; ++j) acc[i][j] = (f32x4){0.f, 0.f, 0.f, 0.f};

  stage(0, 0);
  __syncthreads();

  int buf = 0;
  for (int k0 = 0; k0 < K; k0 += 32, buf ^= 1) {
    if (k0 + 32 < K) stage(buf ^ 1, k0 + 32);

    bf16x8 af[4], bfr[4];
    #pragma unroll
    for (int mi = 0; mi < 4; ++mi) {
      int row = (wr << 6) + (mi << 4) + frow;
      int off = (row << 5) + ((kq ^ ((row >> 1) & 3)) << 3);
      af[mi] = *(const bf16x8*)&lA[buf][off];
    }
    #pragma unroll
    for (int ni = 0; ni < 4; ++ni) {
      int row = (wc << 6) + (ni << 4) + frow;
      int off = (row << 5) + ((kq ^ ((row >> 1) & 3)) << 3);
      bfr[ni] = *(const bf16x8*)&lB[buf][off];
    }
    #pragma unroll
    for (int mi = 0; mi < 4; ++mi)
      #pragma unroll
      for (int ni = 0; ni < 4; ++ni)
        acc[mi][ni] = __builtin_amdgcn_mfma_f32_16x16x32_bf16(
            af[mi], bfr[ni], acc[mi][ni], 0, 0, 0);
    __syncthreads();
  }

  // epilogue: C row = (lane>>4)*4+r, col = lane&15 (m89-verified layout)
  #pragma unroll
  for (int mi = 0; mi < 4; ++mi) {
    #pragma unroll
    for (int ni = 0; ni < 4; ++ni) {
      int col = bcol + (wc << 6) + (ni << 4) + frow;
      int rbase = brow + (wr << 6) + (mi << 4) + (kq << 2);
      if (EPI == 0) {
        if (col < 1024) {
          #pragma unroll
          for (int r = 0; r < 4; ++r) {
            float v = acc[mi][ni][r];
            ((ushort*)outp)[(size_t)(rbase + r) * 1024 + col] =
                f2bf(__expf(-0.5f * v * v));
          }
        } else {
          bool isk = col < 2048;
          int c = col - (isk ? 1024 : 2048);
          int b = rbase >> 12, n = rbase & 4095;
          ushort4 o;
          #pragma unroll
          for (int r = 0; r < 4; ++r) {
            float v = acc[mi][ni][r];
            if (isk) v = __expf(-0.5f * v * v);
            ((ushort*)&o)[r] = f2bf(v);
          }
          ushort* dst = (isk ? kTp : vTp) +
                        ((size_t)(b * 16 + (c >> 6)) * 64 + (c & 63)) * 4096 + n;
          *(ushort4*)dst = o;
        }
      } else {
        #pragma unroll
        for (int r = 0; r < 4; ++r) {
          int row = rbase + r;
          float v = acc[mi][ni][r];
          size_t idx = (size_t)row * F + col;
          if (EPI == 1) {
            ((float*)outp)[idx] = resid[idx] + v + bias[col];   // gamma pre-folded
          } else {
            float t2 = v + bias[col];
            // tanh-approx GELU: 0.5*t*(1+tanh(0.79788456*(t+0.044715*t^3)))
            float y = 0.79788456f * (t2 + 0.044715f * t2 * t2 * t2);
            float e = __expf(2.0f * y);
            float th = (e - 1.0f) / (e + 1.0f);
            ((ushort*)outp)[idx] = f2bf(0.5f * t2 * (1.0f + th));
          }
        }
      }
    }
  }
}

// ---------------- kvT[b,h,e,d] = sum_n v[n,e]*k[n,d]  (MFMA, split-K) ----------------
__global__ __launch_bounds__(256)
void attn_kv_mfma(const ushort* __restrict__ kT, const ushort* __restrict__ vT,
                  float* __restrict__ kvT, float* __restrict__ ksum) {
  __shared__ float red[4][4096];
  int bi = blockIdx.x;
  int ksl = bi & 7, h = (bi >> 3) & 15, b = bi >> 7;
  int tid = threadIdx.x, lane = tid & 63, w = tid >> 6;
  int frow = lane & 15, kq = lane >> 4;
  const size_t bh = (size_t)(b * 16 + h) * 64;
  const ushort* vb = vT + bh * 4096;
  const ushort* kb = kT + bh * 4096;
  int tk0 = ksl * 512 + w * 128;

  f32x4 acc[4][4];
  #pragma unroll
  for (int i = 0; i < 4; ++i)
    #pragma unroll
    for (int j = 0; j < 4; ++j) acc[i][j] = (f32x4){0.f, 0.f, 0.f, 0.f};
  float kpart[4] = {0.f, 0.f, 0.f, 0.f};

  #pragma unroll
  for (int kstep = 0; kstep < 4; ++kstep) {
    int tok = tk0 + kstep * 32 + kq * 8;
    bf16x8 af[4], bfr[4];
    #pragma unroll
    for (int mi = 0; mi < 4; ++mi)
      af[mi] = *(const bf16x8*)&vb[(size_t)(mi * 16 + frow) * 4096 + tok];
    #pragma unroll
    for (int ni = 0; ni < 4; ++ni) {
      bfr[ni] = *(const bf16x8*)&kb[(size_t)(ni * 16 + frow) * 4096 + tok];
      #pragma unroll
      for (int j = 0; j < 8; ++j) kpart[ni] += bf2f((ushort)bfr[ni][j]);
    }
    #pragma unroll
    for (int mi = 0; mi < 4; ++mi)
      #pragma unroll
      for (int ni = 0; ni < 4; ++ni)
        acc[mi][ni] = __builtin_amdgcn_mfma_f32_16x16x32_bf16(
            af[mi], bfr[ni], acc[mi][ni], 0, 0, 0);
  }

  #pragma unroll
  for (int ni = 0; ni < 4; ++ni) {
    kpart[ni] += __shfl_xor(kpart[ni], 16);
    kpart[ni] += __shfl_xor(kpart[ni], 32);
  }
  if (lane < 16) {
    #pragma unroll
    for (int ni = 0; ni < 4; ++ni)
      atomicAdd(&ksum[(b * 16 + h) * 64 + ni * 16 + frow], kpart[ni]);
  }

  #pragma unroll
  for (int mi = 0; mi < 4; ++mi)
    #pragma unroll
    for (int ni = 0; ni < 4; ++ni)
      #pragma unroll
      for (int r = 0; r < 4; ++r)
        red[w][(mi * 16 + kq * 4 + r) * 64 + ni * 16 + frow] = acc[mi][ni][r];
  __syncthreads();
  float* kvg = kvT + (size_t)(b * 16 + h) * 4096;
  for (int i = tid; i < 4096; i += 256) {
    float s = red[0][i] + red[1][i] + red[2][i] + red[3][i];
    atomicAdd(&kvg[i], s);
  }
}

// ---------------- out[n,e] = z * sum_d q[n,d]*kvT[e,d]  (MFMA) ----------------
__global__ __launch_bounds__(256)
void attn_out_mfma(const ushort* __restrict__ qb, const float* __restrict__ kvT,
                   const float* __restrict__ ksum, ushort* __restrict__ ao) {
  __shared__ ushort skv[64 * 72];
  __shared__ float sks[64];
  int bi = blockIdx.x;
  int c = bi & 15, h = (bi >> 4) & 15, b = bi >> 8;
  int tid = threadIdx.x, lane = tid & 63, w = tid >> 6;
  int frow = lane & 15, kq = lane >> 4;
  const float* kvg = kvT + (size_t)(b * 16 + h) * 4096;
  for (int i = tid; i < 4096; i += 256)
    skv[(i >> 6) * 72 + (i & 63)] = f2bf(kvg[i]);
  if (tid < 64) sks[tid] = ksum[(b * 16 + h) * 64 + tid];
  __syncthreads();

  int m0 = b * 4096 + c * 256 + w * 64;
  f32x4 acc[4][4];
  #pragma unroll
  for (int i = 0; i < 4; ++i)
    #pragma unroll
    for (int j = 0; j < 4; ++j) acc[i][j] = (f32x4){0.f, 0.f, 0.f, 0.f};
  float dp[4] = {0.f, 0.f, 0.f, 0.f};

  #pragma unroll
  for (int kst = 0; kst < 2; ++kst) {
    int d0 = kst * 32 + kq * 8;
    bf16x8 af[4], bfr[4];
    #pragma unroll
    for (int mi = 0; mi < 4; ++mi)
      af[mi] = *(const bf16x8*)&qb[(size_t)(m0 + mi * 16 + frow) * 1024 + h * 64 + d0];
    #pragma unroll
    for (int ni = 0; ni < 4; ++ni)
      bfr[ni] = *(const bf16x8*)&skv[(ni * 16 + frow) * 72 + d0];
    #pragma unroll
    for (int mi = 0; mi < 4; ++mi) {
      float s = 0.f;
      #pragma unroll
      for (int j = 0; j < 8; ++j) s += bf2f((ushort)af[mi][j]) * sks[d0 + j];
      dp[mi] += s;
    }
    #pragma unroll
    for (int mi = 0; mi < 4; ++mi)
      #pragma unroll
      for (int ni = 0; ni < 4; ++ni)
        acc[mi][ni] = __builtin_amdgcn_mfma_f32_16x16x32_bf16(
            af[mi], bfr[ni], acc[mi][ni], 0, 0, 0);
  }

  #pragma unroll
  for (int mi = 0; mi < 4; ++mi) {
    dp[mi] += __shfl_xor(dp[mi], 16);
    dp[mi] += __shfl_xor(dp[mi], 32);
  }

  #pragma unroll
  for (int mi = 0; mi < 4; ++mi)
    #pragma unroll
    for (int ni = 0; ni < 4; ++ni)
      #pragma unroll
      for (int r = 0; r < 4; ++r) {
        float dotv = __shfl(dp[mi], (kq << 2) + r);
        float z = 1.f / (dotv + 1e-6f);
        int mrow = m0 + mi * 16 + kq * 4 + r;
        ao[(size_t)mrow * 1024 + h * 64 + ni * 16 + frow] =
            f2bf(acc[mi][ni][r] * z);
      }
}

extern "C" void kernel_launch(void* const* d_in, const int* in_sizes, int n_in,
                              void* d_out, int out_size, void* d_ws, size_t ws_size,
                              hipStream_t stream) {
  const float* x       = (const float*)d_in[0];
  const float* scale1  = (const float*)d_in[1];
  const float* scale2  = (const float*)d_in[2];
  const float* gamma   = (const float*)d_in[3];
  const float* qkv_w   = (const float*)d_in[4];
  const float* proj_w  = (const float*)d_in[5];
  const float* proj_b  = (const float*)d_in[6];
  const float* conv1_w = (const float*)d_in[7];
  const float* conv1_b = (const float*)d_in[8];
  const float* conv2_w = (const float*)d_in[9];
  const float* conv2_b = (const float*)d_in[10];
  float* out = (float*)d_out;

  char* ws = (char*)d_ws;
  size_t off = 0;
  auto alloc = [&](size_t bytes) {
    void* p = ws + off;
    off += (bytes + 255) & ~(size_t)255;
    return p;
  };
  ushort* xn     = (ushort*)alloc((size_t)MTOK * 1024 * 2);
  ushort* qb     = (ushort*)alloc((size_t)MTOK * 1024 * 2);
  ushort* kT     = (ushort*)alloc((size_t)MTOK * 1024 * 2);  // [b,h,d,n]
  ushort* vT     = (ushort*)alloc((size_t)MTOK * 1024 * 2);  // [b,h,e,n]
  ushort* attn_o = (ushort*)alloc((size_t)MTOK * 1024 * 2);
  float*  kvT    = (float*)alloc((size_t)(4 * 16 * 64 * 64 + 4 * 16 * 64) * 4);
  float*  ksum   = kvT + 4 * 16 * 64 * 64;
  ushort* wq = (ushort*)alloc((size_t)3072 * 1024 * 2);
  ushort* wp = (ushort*)alloc((size_t)1024 * 1024 * 2);
  ushort* w1 = (ushort*)alloc((size_t)2048 * 1024 * 2);
  ushort* w2 = (ushort*)alloc((size_t)1024 * 2048 * 2);
  float*  gbp = (float*)alloc(1024 * 4);   // gamma*proj_b
  float*  gbc = (float*)alloc(1024 * 4);   // gamma*conv2_b
  ushort* hid = kT;   // [MTOK][2048] bf16 reuses kT+vT (dead after attention)
  if (off > ws_size) return;

  hipMemsetAsync(kvT, 0, (size_t)(4 * 16 * 64 * 64 + 4 * 16 * 64) * 4, stream);
  f32_to_bf16_k<<<3072, 256, 0, stream>>>(qkv_w, wq, 786432);
  f32_to_bf16_rs_k<<<1024, 256, 0, stream>>>(proj_w, wp, 262144, gamma, 1024);
  f32_to_bf16_k<<<2048, 256, 0, stream>>>(conv1_w, w1, 524288);
  f32_to_bf16_rs_k<<<2048, 256, 0, stream>>>(conv2_w, w2, 524288, gamma, 2048);
  gbias_k<<<4, 256, 0, stream>>>(gamma, proj_b, gbp, 1024);
  gbias_k<<<4, 256, 0, stream>>>(gamma, conv2_b, gbc, 1024);

  // attention branch
  rmsnorm_k<<<MTOK, 256, 0, stream>>>(x, scale1, xn);
  gemm_bt<0><<<128 * 24, 256, 0, stream>>>(xn, wq, qb, nullptr, nullptr,
                                           kT, vT, MTOK, 3072, 1024);
  attn_kv_mfma<<<512, 256, 0, stream>>>(kT, vT, kvT, ksum);
  attn_out_mfma<<<1024, 256, 0, stream>>>(qb, kvT, ksum, attn_o);
  gemm_bt<1><<<128 * 8, 256, 0, stream>>>(attn_o, wp, out, gbp, x,
                                          nullptr, nullptr, MTOK, 1024, 1024);

  // MLP branch (x1 lives in d_out; conv2 epilogue reads+rewrites it)
  rmsnorm_k<<<MTOK, 256, 0, stream>>>(out, scale2, xn);
  gemm_bt<2><<<128 * 16, 256, 0, stream>>>(xn, w1, hid, conv1_b, nullptr,
                                           nullptr, nullptr, MTOK, 2048, 1024);
  gemm_bt<1><<<128 * 8, 256, 0, stream>>>(hid, w2, out, gbc, out,
                                          nullptr, nullptr, MTOK, 1024, 2048);
}